// Round 8
// baseline (170.350 us; speedup 1.0000x reference)
//
#include <hip/hip_runtime.h>

typedef unsigned long long ull;
typedef float f4 __attribute__((ext_vector_type(4)));

#define TOKENS 2048
#define KNN    32
#define VOCAB  32000
#define CAP    2048   // candidate buffer (= 256*8 so fallback can reuse it)

// u64 sorted-descending 8-slot insert (c0..c7)
#define INSK(key) do {                                                       \
    ull k_ = (key);                                                          \
    if (k_ > c7) {                                                           \
        ull tmp_;                                                            \
        if (k_ > c0) { tmp_ = c0; c0 = k_; k_ = tmp_; }                      \
        if (k_ > c1) { tmp_ = c1; c1 = k_; k_ = tmp_; }                      \
        if (k_ > c2) { tmp_ = c2; c2 = k_; k_ = tmp_; }                      \
        if (k_ > c3) { tmp_ = c3; c3 = k_; k_ = tmp_; }                      \
        if (k_ > c4) { tmp_ = c4; c4 = k_; k_ = tmp_; }                      \
        if (k_ > c5) { tmp_ = c5; c5 = k_; k_ = tmp_; }                      \
        if (k_ > c6) { tmp_ = c6; c6 = k_; k_ = tmp_; }                      \
        c7 = (k_ > c7) ? k_ : c7;                                            \
    }                                                                        \
} while (0)

// branch-free sorted-descending 8-float insert (fallback path only)
#define INSF(vv) do {                                                        \
    float x_ = (vv);                                                         \
    if (x_ > t7) {                                                           \
        float h_;                                                            \
        h_ = fmaxf(t0, x_); x_ = fminf(t0, x_); t0 = h_;                     \
        h_ = fmaxf(t1, x_); x_ = fminf(t1, x_); t1 = h_;                     \
        h_ = fmaxf(t2, x_); x_ = fminf(t2, x_); t2 = h_;                     \
        h_ = fmaxf(t3, x_); x_ = fminf(t3, x_); t3 = h_;                     \
        h_ = fmaxf(t4, x_); x_ = fminf(t4, x_); t4 = h_;                     \
        h_ = fmaxf(t5, x_); x_ = fminf(t5, x_); t5 = h_;                     \
        h_ = fmaxf(t6, x_); x_ = fminf(t6, x_); t6 = h_;                     \
        t7 = fmaxf(t7, x_);                                                  \
    }                                                                        \
} while (0)

#define MAX4(v_) fmaxf(fmaxf(v_.x, v_.y), fmaxf(v_.z, v_.w))

__global__ __launch_bounds__(256, 8)
void rc_kernel(const int*   __restrict__ tgt_index,
               const float* __restrict__ knn_dists,
               const float* __restrict__ knn_key,
               const float* __restrict__ net_probs,
               const float* __restrict__ net_sel,
               const float* __restrict__ W_func, const float* __restrict__ b_func,
               const float* __restrict__ W1a,    const float* __restrict__ b1a,
               const float* __restrict__ W1b,    const float* __restrict__ b1b,
               const float* __restrict__ W2a,    const float* __restrict__ b2a,
               const float* __restrict__ W2b,    const float* __restrict__ b2b,
               float* __restrict__ out)
{
    const int t   = blockIdx.x;
    const int tid = threadIdx.x;

    __shared__ float s_max[256];
    __shared__ float s_cand[CAP];
    __shared__ int   s_ncand;
    __shared__ float s_thr;
    __shared__ int   s_tgt[KNN];
    __shared__ float s_dist[KNN];
    __shared__ float s_cnt[KNN];
    __shared__ float s_top8[8];

    if (tid == 0) s_ncand = 0;

    // ---- per-k loads (lanes 0..31) ----
    int   tg = 0;
    float d = 0.f, lk = 0.f, ls = 0.f;
    if (tid < KNN) {
        tg = tgt_index[t * KNN + tid];
        d  = knn_dists[t * KNN + tid];
        lk = logf(knn_key[t * KNN + tid]);
        ls = logf(net_sel[t * KNN + tid]);
        s_tgt[tid]  = tg;
        s_dist[tid] = d;
    }

    const f4* np4 = (const f4*)(net_probs + (size_t)t * VOCAB);
    f4*       o4  = (f4*)(out + (size_t)t * VOCAB);
    const f4  z4  = (f4){0.f, 0.f, 0.f, 0.f};

    // ---- Pass A: branch-free stripe-max scan + fused zero-store ----
    float m = 0.f;
    #pragma unroll
    for (int k = 0; k < 31; ++k) {
        f4 v = np4[tid + (k << 8)];
        o4[tid + (k << 8)] = z4;
        m = fmaxf(m, MAX4(v));
    }
    if (tid < 64) {
        f4 v = np4[tid + (31 << 8)];
        o4[tid + (31 << 8)] = z4;
        m = fmaxf(m, MAX4(v));
    }
    s_max[tid] = m;
    __syncthreads();

    // ---- Threshold: T = 8th largest of the 256 stripe maxes ----
    if (tid < 64) {
        ull c0 = 0, c1 = 0, c2 = 0, c3 = 0, c4 = 0, c5 = 0, c6 = 0, c7 = 0;
        #pragma unroll
        for (int k = 0; k < 4; ++k) {
            int idx = tid + (k << 6);
            ull key = (((ull)__float_as_uint(s_max[idx])) << 32) | (unsigned)idx;
            INSK(key);
        }
        ull g = 0;
        for (int r = 0; r < 8; ++r) {
            g = c0;
            #pragma unroll
            for (int off = 1; off < 64; off <<= 1) {
                ull o = __shfl_xor(g, off);
                if (o > g) g = o;
            }
            if (c0 == g) {   // unique key -> exactly one lane pops
                c0 = c1; c1 = c2; c2 = c3; c3 = c4; c4 = c5; c5 = c6; c6 = c7; c7 = 0;
            }
        }
        if (tid == 0) s_thr = __uint_as_float((unsigned)(g >> 32));  // 8th value
    }
    __syncthreads();
    const float T = s_thr;

    // ---- Pass B: collect candidates >= T (row is L2/L3-hot; pass is rare-branch) ----
    #pragma unroll 4
    for (int k = 0; k < 31; ++k) {
        f4 v = np4[tid + (k << 8)];
        if (MAX4(v) >= T) {
            if (v.x >= T) { int p = atomicAdd(&s_ncand, 1); if (p < CAP) s_cand[p] = v.x; }
            if (v.y >= T) { int p = atomicAdd(&s_ncand, 1); if (p < CAP) s_cand[p] = v.y; }
            if (v.z >= T) { int p = atomicAdd(&s_ncand, 1); if (p < CAP) s_cand[p] = v.z; }
            if (v.w >= T) { int p = atomicAdd(&s_ncand, 1); if (p < CAP) s_cand[p] = v.w; }
        }
    }
    if (tid < 64) {
        f4 v = np4[tid + (31 << 8)];
        if (MAX4(v) >= T) {
            if (v.x >= T) { int p = atomicAdd(&s_ncand, 1); if (p < CAP) s_cand[p] = v.x; }
            if (v.y >= T) { int p = atomicAdd(&s_ncand, 1); if (p < CAP) s_cand[p] = v.y; }
            if (v.z >= T) { int p = atomicAdd(&s_ncand, 1); if (p < CAP) s_cand[p] = v.z; }
            if (v.w >= T) { int p = atomicAdd(&s_ncand, 1); if (p < CAP) s_cand[p] = v.w; }
        }
    }
    __syncthreads();
    const int n = s_ncand;

    if (n <= CAP) {
        // merge candidates -> exact top-8 values
        if (tid < 64) {
            ull c0 = 0, c1 = 0, c2 = 0, c3 = 0, c4 = 0, c5 = 0, c6 = 0, c7 = 0;
            for (int i = tid; i < n; i += 64) {
                ull key = (((ull)__float_as_uint(s_cand[i])) << 32) | (unsigned)i;
                INSK(key);
            }
            for (int r = 0; r < 8; ++r) {
                ull g = c0;
                #pragma unroll
                for (int off = 1; off < 64; off <<= 1) {
                    ull o = __shfl_xor(g, off);
                    if (o > g) g = o;
                }
                if (c0 == g && g != 0ULL) {
                    c0 = c1; c1 = c2; c2 = c3; c3 = c4; c4 = c5; c5 = c6; c6 = c7; c7 = 0;
                }
                if (tid == 0) s_top8[r] = __uint_as_float((unsigned)(g >> 32));
            }
        }
    } else {
        // fallback (adversarial ties): per-thread exact top-8 + full merge
        float t0 = 0.f, t1 = 0.f, t2 = 0.f, t3 = 0.f,
              t4 = 0.f, t5 = 0.f, t6 = 0.f, t7 = 0.f;
        for (int k = 0; k < 31; ++k) {
            f4 v = np4[tid + (k << 8)];
            float mm = MAX4(v);
            if (mm > t7) { INSF(v.x); INSF(v.y); INSF(v.z); INSF(v.w); }
        }
        if (tid < 64) {
            f4 v = np4[tid + (31 << 8)];
            float mm = MAX4(v);
            if (mm > t7) { INSF(v.x); INSF(v.y); INSF(v.z); INSF(v.w); }
        }
        __syncthreads();   // s_cand reuse: everyone past the collect phase
        s_cand[tid * 8 + 0] = t0;  s_cand[tid * 8 + 1] = t1;
        s_cand[tid * 8 + 2] = t2;  s_cand[tid * 8 + 3] = t3;
        s_cand[tid * 8 + 4] = t4;  s_cand[tid * 8 + 5] = t5;
        s_cand[tid * 8 + 6] = t6;  s_cand[tid * 8 + 7] = t7;
        __syncthreads();
        if (tid < 64) {
            ull c0 = 0, c1 = 0, c2 = 0, c3 = 0, c4 = 0, c5 = 0, c6 = 0, c7 = 0;
            for (int k = 0; k < 32; ++k) {
                int idx = tid + (k << 6);
                ull key = (((ull)__float_as_uint(s_cand[idx])) << 32) | (unsigned)idx;
                INSK(key);
            }
            for (int r = 0; r < 8; ++r) {
                ull g = c0;
                #pragma unroll
                for (int off = 1; off < 64; off <<= 1) {
                    ull o = __shfl_xor(g, off);
                    if (o > g) g = o;
                }
                if (c0 == g) {
                    c0 = c1; c1 = c2; c2 = c3; c3 = c4; c4 = c5; c5 = c6; c6 = c7; c7 = 0;
                }
                if (tid == 0) s_top8[r] = __uint_as_float((unsigned)(g >> 32));
            }
        }
    }
    __syncthreads();

    // ---- Phase 3a: label counts (distinct, reference never counts label 0) ----
    if (tid < KNN) {
        int fo = (tg != 0) ? 1 : 0;
        if (fo) {
            for (int j = 0; j < tid; ++j)
                if (s_tgt[j] == tg) { fo = 0; break; }
        }
        int c = fo;
        #pragma unroll
        for (int off = 1; off < KNN; off <<= 1) {
            int n2 = __shfl_up(c, off, KNN);
            if (tid >= off) c += n2;
        }
        s_cnt[tid] = (float)c;
    }
    __syncthreads();

    // ---- Phase 3b: tiny MLPs, softmaxes, scatter ----
    if (tid < KNN) {
        // noise_logit: Linear(2,4) -> tanh -> Linear(4,1)
        float noise = b1b[0];
        #pragma unroll
        for (int j = 0; j < 4; ++j) {
            float z = tanhf(W1a[2 * j] * lk + W1a[2 * j + 1] * ls + b1a[j]);
            noise += W1b[j] * z;
        }

        // sim_lambda = W_func . [log(top8) | log_key | log_sel] + b_func
        float sp = W_func[8 + tid] * lk + W_func[40 + tid] * ls;
        if (tid < 8) sp += W_func[tid] * logf(s_top8[tid]);
        #pragma unroll
        for (int off = 16; off; off >>= 1) sp += __shfl_xor(sp, off, KNN);
        float sim = sp + b_func[0];

        // lambda_logit: Linear(64,32) -> tanh -> Linear(32,2); lane = hidden unit
        float h = b2a[tid];
        const float* wr = W2a + tid * 64;
        #pragma unroll 8
        for (int i = 0; i < KNN; ++i) h += wr[i] * s_dist[i];
        #pragma unroll 8
        for (int i = 0; i < KNN; ++i) h += wr[KNN + i] * s_cnt[i];
        h = tanhf(h);
        float p0 = W2b[tid] * h;
        float p1 = W2b[KNN + tid] * h;
        #pragma unroll
        for (int off = 16; off; off >>= 1) {
            p0 += __shfl_xor(p0, off, KNN);
            p1 += __shfl_xor(p1, off, KNN);
        }
        float l0 = p0 + b2b[0];
        float l1 = p1 + b2b[1];

        float tempe = 1.f / (1.f + expf(-l1));          // sigmoid(l1)
        float lam   = 1.f / (1.f + expf(-(l0 - sim)));  // softmax([l0,sim])[0]

        // probs = softmax(-d*tempe + noise) over K
        float logit = -d * tempe + noise;
        float mx = logit;
        #pragma unroll
        for (int off = 16; off; off >>= 1) mx = fmaxf(mx, __shfl_xor(mx, off, KNN));
        float e = expf(logit - mx);
        float se = e;
        #pragma unroll
        for (int off = 16; off; off >>= 1) se += __shfl_xor(se, off, KNN);
        float p = e / se;

        // scatter, last-occurrence-wins on duplicate indices (numpy semantics)
        bool wrte = true;
        for (int j = tid + 1; j < KNN; ++j)
            if (s_tgt[j] == tg) { wrte = false; break; }
        if (wrte) out[(size_t)t * VOCAB + tg] = p;

        if (tid == 0) out[(size_t)TOKENS * VOCAB + t] = lam;
    }
}

extern "C" void kernel_launch(void* const* d_in, const int* in_sizes, int n_in,
                              void* d_out, int out_size, void* d_ws, size_t ws_size,
                              hipStream_t stream) {
    rc_kernel<<<TOKENS, 256, 0, stream>>>(
        (const int*)  d_in[0],   // tgt_index
        (const float*)d_in[1],   // knn_dists
        (const float*)d_in[2],   // knn_key_feature
        (const float*)d_in[3],   // network_probs
        (const float*)d_in[4],   // network_select_probs
        (const float*)d_in[5],  (const float*)d_in[6],   // W_func, b_func
        (const float*)d_in[7],  (const float*)d_in[8],   // W1a, b1a
        (const float*)d_in[9],  (const float*)d_in[10],  // W1b, b1b
        (const float*)d_in[11], (const float*)d_in[12],  // W2a, b2a
        (const float*)d_in[13], (const float*)d_in[14],  // W2b, b2b
        (float*)d_out);
}

// Round 9
// 156.492 us; speedup vs baseline: 1.0886x; 1.0886x over previous
//
#include <hip/hip_runtime.h>

typedef unsigned long long ull;
typedef float f4 __attribute__((ext_vector_type(4)));

#define TOKENS 2048
#define KNN    32
#define VOCAB  32000
#define QPT    4            // blocks (quarters) per token
#define BF4    2000         // float4s per block = 8000/QPT
#define CAP    2048         // candidate buffer (=256*8 so fallback reuses it)

// u64 sorted-descending 8-slot insert (c0..c7)
#define INSK(key) do {                                                       \
    ull k_ = (key);                                                          \
    if (k_ > c7) {                                                           \
        ull tmp_;                                                            \
        if (k_ > c0) { tmp_ = c0; c0 = k_; k_ = tmp_; }                      \
        if (k_ > c1) { tmp_ = c1; c1 = k_; k_ = tmp_; }                      \
        if (k_ > c2) { tmp_ = c2; c2 = k_; k_ = tmp_; }                      \
        if (k_ > c3) { tmp_ = c3; c3 = k_; k_ = tmp_; }                      \
        if (k_ > c4) { tmp_ = c4; c4 = k_; k_ = tmp_; }                      \
        if (k_ > c5) { tmp_ = c5; c5 = k_; k_ = tmp_; }                      \
        if (k_ > c6) { tmp_ = c6; c6 = k_; k_ = tmp_; }                      \
        c7 = (k_ > c7) ? k_ : c7;                                            \
    }                                                                        \
} while (0)

// branch-free sorted-descending 8-float insert (fallback path only)
#define INSF(vv) do {                                                        \
    float x_ = (vv);                                                         \
    if (x_ > t7) {                                                           \
        float h_;                                                            \
        h_ = fmaxf(t0, x_); x_ = fminf(t0, x_); t0 = h_;                     \
        h_ = fmaxf(t1, x_); x_ = fminf(t1, x_); t1 = h_;                     \
        h_ = fmaxf(t2, x_); x_ = fminf(t2, x_); t2 = h_;                     \
        h_ = fmaxf(t3, x_); x_ = fminf(t3, x_); t3 = h_;                     \
        h_ = fmaxf(t4, x_); x_ = fminf(t4, x_); t4 = h_;                     \
        h_ = fmaxf(t5, x_); x_ = fminf(t5, x_); t5 = h_;                     \
        h_ = fmaxf(t6, x_); x_ = fminf(t6, x_); t6 = h_;                     \
        t7 = fmaxf(t7, x_);                                                  \
    }                                                                        \
} while (0)

#define MAX4(v_) fmaxf(fmaxf(v_.x, v_.y), fmaxf(v_.z, v_.w))

#define COLLECT(v_) do {                                                     \
    if (MAX4(v_) >= T) {                                                     \
        if (v_.x >= T) { int p = atomicAdd(&s_n, 1); if (p < CAP) s_cand[p] = v_.x; } \
        if (v_.y >= T) { int p = atomicAdd(&s_n, 1); if (p < CAP) s_cand[p] = v_.y; } \
        if (v_.z >= T) { int p = atomicAdd(&s_n, 1); if (p < CAP) s_cand[p] = v_.z; } \
        if (v_.w >= T) { int p = atomicAdd(&s_n, 1); if (p < CAP) s_cand[p] = v_.w; } \
    }                                                                        \
} while (0)

// ---------------- K1: read-only scan, block-local exact top-8 ----------------
__global__ __launch_bounds__(256, 8)
void k1_scan(const float* __restrict__ net_probs, float* __restrict__ ws)
{
    const int bid = blockIdx.x;
    const int t   = bid >> 2;
    const int q   = bid & 3;
    const int tid = threadIdx.x;

    __shared__ float s_max[256];
    __shared__ float s_cand[CAP];
    __shared__ int   s_n;
    __shared__ float s_thr;
    __shared__ float s_top8[8];

    if (tid == 0) s_n = 0;

    const f4* np4 = (const f4*)(net_probs + (size_t)t * VOCAB) + q * BF4;

    // pass 1: branch-free stripe max (2000 f4 = 7*256 + 208)
    float m = 0.f;
    #pragma unroll
    for (int k = 0; k < 7; ++k) {
        f4 v = np4[tid + (k << 8)];
        m = fmaxf(m, MAX4(v));
    }
    if (tid < 208) {
        f4 v = np4[tid + 1792];
        m = fmaxf(m, MAX4(v));
    }
    s_max[tid] = m;
    __syncthreads();

    // threshold: 8th largest of the 256 stripe maxes (one wave)
    if (tid < 64) {
        ull c0 = 0, c1 = 0, c2 = 0, c3 = 0, c4 = 0, c5 = 0, c6 = 0, c7 = 0;
        #pragma unroll
        for (int k = 0; k < 4; ++k) {
            int idx = tid + (k << 6);
            ull key = (((ull)__float_as_uint(s_max[idx])) << 32) | (unsigned)idx;
            INSK(key);
        }
        ull g = 0;
        for (int r = 0; r < 8; ++r) {
            g = c0;
            #pragma unroll
            for (int off = 1; off < 64; off <<= 1) {
                ull o = __shfl_xor(g, off);
                if (o > g) g = o;
            }
            if (c0 == g) {   // unique key -> exactly one lane pops
                c0 = c1; c1 = c2; c2 = c3; c3 = c4; c4 = c5; c5 = c6; c6 = c7; c7 = 0;
            }
        }
        if (tid == 0) s_thr = __uint_as_float((unsigned)(g >> 32));
    }
    __syncthreads();
    const float T = s_thr;

    // pass 2: local re-scan (block's 32 KB, cache-hot), collect >= T
    #pragma unroll
    for (int k = 0; k < 7; ++k) {
        f4 v = np4[tid + (k << 8)];
        COLLECT(v);
    }
    if (tid < 208) {
        f4 v = np4[tid + 1792];
        COLLECT(v);
    }
    __syncthreads();
    const int n = s_n;

    if (n <= CAP) {
        if (tid < 64) {
            ull c0 = 0, c1 = 0, c2 = 0, c3 = 0, c4 = 0, c5 = 0, c6 = 0, c7 = 0;
            for (int i = tid; i < n; i += 64) {
                ull key = (((ull)__float_as_uint(s_cand[i])) << 32) | (unsigned)i;
                INSK(key);
            }
            for (int r = 0; r < 8; ++r) {
                ull g = c0;
                #pragma unroll
                for (int off = 1; off < 64; off <<= 1) {
                    ull o = __shfl_xor(g, off);
                    if (o > g) g = o;
                }
                if (c0 == g && g != 0ULL) {
                    c0 = c1; c1 = c2; c2 = c3; c3 = c4; c4 = c5; c5 = c6; c6 = c7; c7 = 0;
                }
                if (tid == 0) s_top8[r] = __uint_as_float((unsigned)(g >> 32));
            }
        }
    } else {
        // fallback (adversarial ties): per-thread exact top-8 + full merge
        float t0 = 0.f, t1 = 0.f, t2 = 0.f, t3 = 0.f,
              t4 = 0.f, t5 = 0.f, t6 = 0.f, t7 = 0.f;
        for (int k = 0; k < 7; ++k) {
            f4 v = np4[tid + (k << 8)];
            if (MAX4(v) > t7) { INSF(v.x); INSF(v.y); INSF(v.z); INSF(v.w); }
        }
        if (tid < 208) {
            f4 v = np4[tid + 1792];
            if (MAX4(v) > t7) { INSF(v.x); INSF(v.y); INSF(v.z); INSF(v.w); }
        }
        s_cand[tid * 8 + 0] = t0;  s_cand[tid * 8 + 1] = t1;
        s_cand[tid * 8 + 2] = t2;  s_cand[tid * 8 + 3] = t3;
        s_cand[tid * 8 + 4] = t4;  s_cand[tid * 8 + 5] = t5;
        s_cand[tid * 8 + 6] = t6;  s_cand[tid * 8 + 7] = t7;
        __syncthreads();
        if (tid < 64) {
            ull c0 = 0, c1 = 0, c2 = 0, c3 = 0, c4 = 0, c5 = 0, c6 = 0, c7 = 0;
            for (int k = 0; k < 32; ++k) {
                int idx = tid + (k << 6);
                ull key = (((ull)__float_as_uint(s_cand[idx])) << 32) | (unsigned)idx;
                INSK(key);
            }
            for (int r = 0; r < 8; ++r) {
                ull g = c0;
                #pragma unroll
                for (int off = 1; off < 64; off <<= 1) {
                    ull o = __shfl_xor(g, off);
                    if (o > g) g = o;
                }
                if (c0 == g) {
                    c0 = c1; c1 = c2; c2 = c3; c3 = c4; c4 = c5; c5 = c6; c6 = c7; c7 = 0;
                }
                if (tid == 0) s_top8[r] = __uint_as_float((unsigned)(g >> 32));
            }
        }
    }
    __syncthreads();

    if (tid < 8) ws[(size_t)bid * 8 + tid] = s_top8[tid];
}

// ---------------- K2: write-only zero-fill + merge + math + scatter ----------------
__global__ __launch_bounds__(256, 8)
void k2_final(const int*   __restrict__ tgt_index,
              const float* __restrict__ knn_dists,
              const float* __restrict__ knn_key,
              const float* __restrict__ net_sel,
              const float* __restrict__ W_func, const float* __restrict__ b_func,
              const float* __restrict__ W1a,    const float* __restrict__ b1a,
              const float* __restrict__ W1b,    const float* __restrict__ b1b,
              const float* __restrict__ W2a,    const float* __restrict__ b2a,
              const float* __restrict__ W2b,    const float* __restrict__ b2b,
              const float* __restrict__ ws,
              float* __restrict__ out)
{
    const int t   = blockIdx.x;
    const int tid = threadIdx.x;

    __shared__ float s_c[QPT * 8];
    __shared__ int   s_tgt[KNN];
    __shared__ float s_dist[KNN];
    __shared__ float s_cnt[KNN];
    __shared__ float s_top8[8];

    // small per-k loads (lanes 0..31) + candidate values
    int   tg = 0;
    float d = 0.f, lk = 0.f, ls = 0.f;
    if (tid < KNN) {
        tg = tgt_index[t * KNN + tid];
        d  = knn_dists[t * KNN + tid];
        lk = logf(knn_key[t * KNN + tid]);
        ls = logf(net_sel[t * KNN + tid]);
        s_tgt[tid]  = tg;
        s_dist[tid] = d;
    }
    if (tid < QPT * 8) s_c[tid] = ws[(size_t)t * (QPT * 8) + tid];

    // zero-fill the output row: pure write stream
    f4*      o4 = (f4*)(out + (size_t)t * VOCAB);
    const f4 z4 = (f4){0.f, 0.f, 0.f, 0.f};
    #pragma unroll
    for (int k = 0; k < 31; ++k) o4[tid + (k << 8)] = z4;
    if (tid < 64) o4[tid + (31 << 8)] = z4;
    __syncthreads();   // zeros drained; s_tgt/s_c visible

    // merge the 32 block-candidates -> global top-8 values (one wave)
    if (tid < 64) {
        ull c0 = 0, c1 = 0, c2 = 0, c3 = 0, c4 = 0, c5 = 0, c6 = 0, c7 = 0;
        if (tid < QPT * 8) {
            ull key = (((ull)__float_as_uint(s_c[tid])) << 32) | (unsigned)tid;
            INSK(key);
        }
        for (int r = 0; r < 8; ++r) {
            ull g = c0;
            #pragma unroll
            for (int off = 1; off < 64; off <<= 1) {
                ull o = __shfl_xor(g, off);
                if (o > g) g = o;
            }
            if (c0 == g && g != 0ULL) {
                c0 = c1; c1 = c2; c2 = c3; c3 = c4; c4 = c5; c5 = c6; c6 = c7; c7 = 0;
            }
            if (tid == 0) s_top8[r] = __uint_as_float((unsigned)(g >> 32));
        }
    }
    __syncthreads();

    // label counts (distinct, reference never counts label 0)
    if (tid < KNN) {
        int fo = (tg != 0) ? 1 : 0;
        if (fo) {
            for (int j = 0; j < tid; ++j)
                if (s_tgt[j] == tg) { fo = 0; break; }
        }
        int c = fo;
        #pragma unroll
        for (int off = 1; off < KNN; off <<= 1) {
            int n2 = __shfl_up(c, off, KNN);
            if (tid >= off) c += n2;
        }
        s_cnt[tid] = (float)c;
    }
    __syncthreads();

    // tiny MLPs, softmaxes, scatter
    if (tid < KNN) {
        // noise_logit: Linear(2,4) -> tanh -> Linear(4,1)
        float noise = b1b[0];
        #pragma unroll
        for (int j = 0; j < 4; ++j) {
            float z = tanhf(W1a[2 * j] * lk + W1a[2 * j + 1] * ls + b1a[j]);
            noise += W1b[j] * z;
        }

        // sim_lambda = W_func . [log(top8) | log_key | log_sel] + b_func
        float sp = W_func[8 + tid] * lk + W_func[40 + tid] * ls;
        if (tid < 8) sp += W_func[tid] * logf(s_top8[tid]);
        #pragma unroll
        for (int off = 16; off; off >>= 1) sp += __shfl_xor(sp, off, KNN);
        float sim = sp + b_func[0];

        // lambda_logit: Linear(64,32) -> tanh -> Linear(32,2); lane = hidden unit
        float h = b2a[tid];
        const float* wr = W2a + tid * 64;
        #pragma unroll 8
        for (int i = 0; i < KNN; ++i) h += wr[i] * s_dist[i];
        #pragma unroll 8
        for (int i = 0; i < KNN; ++i) h += wr[KNN + i] * s_cnt[i];
        h = tanhf(h);
        float p0 = W2b[tid] * h;
        float p1 = W2b[KNN + tid] * h;
        #pragma unroll
        for (int off = 16; off; off >>= 1) {
            p0 += __shfl_xor(p0, off, KNN);
            p1 += __shfl_xor(p1, off, KNN);
        }
        float l0 = p0 + b2b[0];
        float l1 = p1 + b2b[1];

        float tempe = 1.f / (1.f + expf(-l1));          // sigmoid(l1)
        float lam   = 1.f / (1.f + expf(-(l0 - sim)));  // softmax([l0,sim])[0]

        // probs = softmax(-d*tempe + noise) over K
        float logit = -d * tempe + noise;
        float mx = logit;
        #pragma unroll
        for (int off = 16; off; off >>= 1) mx = fmaxf(mx, __shfl_xor(mx, off, KNN));
        float e = expf(logit - mx);
        float se = e;
        #pragma unroll
        for (int off = 16; off; off >>= 1) se += __shfl_xor(se, off, KNN);
        float p = e / se;

        // scatter, last-occurrence-wins on duplicate indices (numpy semantics)
        bool wrte = true;
        for (int j = tid + 1; j < KNN; ++j)
            if (s_tgt[j] == tg) { wrte = false; break; }
        if (wrte) out[(size_t)t * VOCAB + tg] = p;

        if (tid == 0) out[(size_t)TOKENS * VOCAB + t] = lam;
    }
}

extern "C" void kernel_launch(void* const* d_in, const int* in_sizes, int n_in,
                              void* d_out, int out_size, void* d_ws, size_t ws_size,
                              hipStream_t stream) {
    float* ws = (float*)d_ws;   // needs TOKENS*QPT*8*4 = 256 KB

    k1_scan<<<TOKENS * QPT, 256, 0, stream>>>(
        (const float*)d_in[3],   // network_probs
        ws);

    k2_final<<<TOKENS, 256, 0, stream>>>(
        (const int*)  d_in[0],   // tgt_index
        (const float*)d_in[1],   // knn_dists
        (const float*)d_in[2],   // knn_key_feature
        (const float*)d_in[4],   // network_select_probs
        (const float*)d_in[5],  (const float*)d_in[6],   // W_func, b_func
        (const float*)d_in[7],  (const float*)d_in[8],   // W1a, b1a
        (const float*)d_in[9],  (const float*)d_in[10],  // W1b, b1b
        (const float*)d_in[11], (const float*)d_in[12],  // W2a, b2a
        (const float*)d_in[13], (const float*)d_in[14],  // W2b, b2b
        ws,
        (float*)d_out);
}

// Round 10
// 152.320 us; speedup vs baseline: 1.1184x; 1.0274x over previous
//
#include <hip/hip_runtime.h>

typedef unsigned long long ull;
typedef float f4 __attribute__((ext_vector_type(4)));

#define TOKENS 2048
#define KNN    32
#define VOCAB  32000
#define QPT    4            // quarters per token
#define BF4    2000         // float4s per quarter (= 8000/QPT)
#define CAP    2048         // candidate buffer (=256*8 so fallback reuses it)

// u64 sorted-descending 8-slot insert (c0..c7)
#define INSK(key) do {                                                       \
    ull k_ = (key);                                                          \
    if (k_ > c7) {                                                           \
        ull tmp_;                                                            \
        if (k_ > c0) { tmp_ = c0; c0 = k_; k_ = tmp_; }                      \
        if (k_ > c1) { tmp_ = c1; c1 = k_; k_ = tmp_; }                      \
        if (k_ > c2) { tmp_ = c2; c2 = k_; k_ = tmp_; }                      \
        if (k_ > c3) { tmp_ = c3; c3 = k_; k_ = tmp_; }                      \
        if (k_ > c4) { tmp_ = c4; c4 = k_; k_ = tmp_; }                      \
        if (k_ > c5) { tmp_ = c5; c5 = k_; k_ = tmp_; }                      \
        if (k_ > c6) { tmp_ = c6; c6 = k_; k_ = tmp_; }                      \
        c7 = (k_ > c7) ? k_ : c7;                                            \
    }                                                                        \
} while (0)

// branch-free sorted-descending 8-float insert (fallback path only)
#define INSF(vv) do {                                                        \
    float x_ = (vv);                                                         \
    if (x_ > t7) {                                                           \
        float h_;                                                            \
        h_ = fmaxf(t0, x_); x_ = fminf(t0, x_); t0 = h_;                     \
        h_ = fmaxf(t1, x_); x_ = fminf(t1, x_); t1 = h_;                     \
        h_ = fmaxf(t2, x_); x_ = fminf(t2, x_); t2 = h_;                     \
        h_ = fmaxf(t3, x_); x_ = fminf(t3, x_); t3 = h_;                     \
        h_ = fmaxf(t4, x_); x_ = fminf(t4, x_); t4 = h_;                     \
        h_ = fmaxf(t5, x_); x_ = fminf(t5, x_); t5 = h_;                     \
        h_ = fmaxf(t6, x_); x_ = fminf(t6, x_); t6 = h_;                     \
        t7 = fmaxf(t7, x_);                                                  \
    }                                                                        \
} while (0)

#define MAX4(v_) fmaxf(fmaxf(v_.x, v_.y), fmaxf(v_.z, v_.w))

#define COLLECT(v_) do {                                                     \
    if (v_.x >= T) { int p = atomicAdd(&s_n, 1); if (p < CAP) s_cand[p] = v_.x; } \
    if (v_.y >= T) { int p = atomicAdd(&s_n, 1); if (p < CAP) s_cand[p] = v_.y; } \
    if (v_.z >= T) { int p = atomicAdd(&s_n, 1); if (p < CAP) s_cand[p] = v_.z; } \
    if (v_.w >= T) { int p = atomicAdd(&s_n, 1); if (p < CAP) s_cand[p] = v_.w; } \
} while (0)

// --------- K1: even blocks = pure-read scan; odd blocks = pure-write zero ---------
__global__ __launch_bounds__(256, 8)
void k1_big(const float* __restrict__ net_probs,
            float* __restrict__ out,
            float* __restrict__ ws)
{
    const int bid = blockIdx.x;
    const int tid = threadIdx.x;
    const int id  = bid >> 1;          // quarter id: 0..8191
    const int t   = id >> 2;           // token
    const int q   = id & 3;            // quarter within token

    if (bid & 1) {
        // ---- zero-fill quarter: pure write stream ----
        f4*      o4 = (f4*)(out + (size_t)t * VOCAB) + q * BF4;
        const f4 z4 = (f4){0.f, 0.f, 0.f, 0.f};
        #pragma unroll
        for (int k = 0; k < 7; ++k) o4[tid + (k << 8)] = z4;
        if (tid < 208) o4[tid + 1792] = z4;
        return;
    }

    // ---- scan quarter: pure read stream ----
    __shared__ float s_max[256];
    __shared__ float s_cand[CAP];
    __shared__ int   s_n;
    __shared__ float s_thr;
    __shared__ float s_top8[8];

    if (tid == 0) s_n = 0;

    const f4* np4 = (const f4*)(net_probs + (size_t)t * VOCAB) + q * BF4;

    // pass 1: branch-free stripe max (2000 f4 = 7*256 + 208)
    float m = 0.f;
    #pragma unroll
    for (int k = 0; k < 7; ++k) {
        f4 v = np4[tid + (k << 8)];
        m = fmaxf(m, MAX4(v));
    }
    if (tid < 208) {
        f4 v = np4[tid + 1792];
        m = fmaxf(m, MAX4(v));
    }
    s_max[tid] = m;
    __syncthreads();

    // threshold: T = 8th largest of the 256 stripe maxes (one wave)
    if (tid < 64) {
        ull c0 = 0, c1 = 0, c2 = 0, c3 = 0, c4 = 0, c5 = 0, c6 = 0, c7 = 0;
        #pragma unroll
        for (int k = 0; k < 4; ++k) {
            int idx = tid + (k << 6);
            ull key = (((ull)__float_as_uint(s_max[idx])) << 32) | (unsigned)idx;
            INSK(key);
        }
        ull g = 0;
        for (int r = 0; r < 8; ++r) {
            g = c0;
            #pragma unroll
            for (int off = 1; off < 64; off <<= 1) {
                ull o = __shfl_xor(g, off);
                if (o > g) g = o;
            }
            if (c0 == g) {   // unique key -> exactly one lane pops
                c0 = c1; c1 = c2; c2 = c3; c3 = c4; c4 = c5; c5 = c6; c6 = c7; c7 = 0;
            }
        }
        if (tid == 0) s_thr = __uint_as_float((unsigned)(g >> 32));
    }
    __syncthreads();
    const float T = s_thr;

    // pass 2: ONLY qualifying stripes (max >= T, ~8 of 256) re-read: L2-hot, ~0.5 KB
    if (m >= T) {
        #pragma unroll
        for (int k = 0; k < 7; ++k) {
            f4 v = np4[tid + (k << 8)];
            COLLECT(v);
        }
        if (tid < 208) {
            f4 v = np4[tid + 1792];
            COLLECT(v);
        }
    }
    __syncthreads();
    const int n = s_n;

    if (n <= CAP) {
        if (tid < 64) {
            ull c0 = 0, c1 = 0, c2 = 0, c3 = 0, c4 = 0, c5 = 0, c6 = 0, c7 = 0;
            for (int i = tid; i < n; i += 64) {
                ull key = (((ull)__float_as_uint(s_cand[i])) << 32) | (unsigned)i;
                INSK(key);
            }
            for (int r = 0; r < 8; ++r) {
                ull g = c0;
                #pragma unroll
                for (int off = 1; off < 64; off <<= 1) {
                    ull o = __shfl_xor(g, off);
                    if (o > g) g = o;
                }
                if (c0 == g && g != 0ULL) {
                    c0 = c1; c1 = c2; c2 = c3; c3 = c4; c4 = c5; c5 = c6; c6 = c7; c7 = 0;
                }
                if (tid == 0) s_top8[r] = __uint_as_float((unsigned)(g >> 32));
            }
        }
    } else {
        // fallback (adversarial ties): per-thread exact top-8 + full merge
        float t0 = 0.f, t1 = 0.f, t2 = 0.f, t3 = 0.f,
              t4 = 0.f, t5 = 0.f, t6 = 0.f, t7 = 0.f;
        for (int k = 0; k < 7; ++k) {
            f4 v = np4[tid + (k << 8)];
            if (MAX4(v) > t7) { INSF(v.x); INSF(v.y); INSF(v.z); INSF(v.w); }
        }
        if (tid < 208) {
            f4 v = np4[tid + 1792];
            if (MAX4(v) > t7) { INSF(v.x); INSF(v.y); INSF(v.z); INSF(v.w); }
        }
        __syncthreads();
        s_cand[tid * 8 + 0] = t0;  s_cand[tid * 8 + 1] = t1;
        s_cand[tid * 8 + 2] = t2;  s_cand[tid * 8 + 3] = t3;
        s_cand[tid * 8 + 4] = t4;  s_cand[tid * 8 + 5] = t5;
        s_cand[tid * 8 + 6] = t6;  s_cand[tid * 8 + 7] = t7;
        __syncthreads();
        if (tid < 64) {
            ull c0 = 0, c1 = 0, c2 = 0, c3 = 0, c4 = 0, c5 = 0, c6 = 0, c7 = 0;
            for (int k = 0; k < 32; ++k) {
                int idx = tid + (k << 6);
                ull key = (((ull)__float_as_uint(s_cand[idx])) << 32) | (unsigned)idx;
                INSK(key);
            }
            for (int r = 0; r < 8; ++r) {
                ull g = c0;
                #pragma unroll
                for (int off = 1; off < 64; off <<= 1) {
                    ull o = __shfl_xor(g, off);
                    if (o > g) g = o;
                }
                if (c0 == g) {
                    c0 = c1; c1 = c2; c2 = c3; c3 = c4; c4 = c5; c5 = c6; c6 = c7; c7 = 0;
                }
                if (tid == 0) s_top8[r] = __uint_as_float((unsigned)(g >> 32));
            }
        }
    }
    __syncthreads();

    if (tid < 8) ws[(size_t)id * 8 + tid] = s_top8[tid];
}

// --------- K2: merge quarter-top8s + tiny math + scatter (no bulk traffic) ---------
__global__ __launch_bounds__(256, 8)
void k2_final(const int*   __restrict__ tgt_index,
              const float* __restrict__ knn_dists,
              const float* __restrict__ knn_key,
              const float* __restrict__ net_sel,
              const float* __restrict__ W_func, const float* __restrict__ b_func,
              const float* __restrict__ W1a,    const float* __restrict__ b1a,
              const float* __restrict__ W1b,    const float* __restrict__ b1b,
              const float* __restrict__ W2a,    const float* __restrict__ b2a,
              const float* __restrict__ W2b,    const float* __restrict__ b2b,
              const float* __restrict__ ws,
              float* __restrict__ out)
{
    const int t   = blockIdx.x;
    const int tid = threadIdx.x;

    __shared__ float s_c[QPT * 8];
    __shared__ int   s_tgt[KNN];
    __shared__ float s_dist[KNN];
    __shared__ float s_cnt[KNN];
    __shared__ float s_top8[8];

    int   tg = 0;
    float d = 0.f, lk = 0.f, ls = 0.f;
    if (tid < KNN) {
        tg = tgt_index[t * KNN + tid];
        d  = knn_dists[t * KNN + tid];
        lk = logf(knn_key[t * KNN + tid]);
        ls = logf(net_sel[t * KNN + tid]);
        s_tgt[tid]  = tg;
        s_dist[tid] = d;
    }
    if (tid < QPT * 8) s_c[tid] = ws[(size_t)t * (QPT * 8) + tid];
    __syncthreads();

    // merge the 32 quarter-candidates -> global top-8 values (one wave)
    if (tid < 64) {
        ull c0 = 0, c1 = 0, c2 = 0, c3 = 0, c4 = 0, c5 = 0, c6 = 0, c7 = 0;
        if (tid < QPT * 8) {
            ull key = (((ull)__float_as_uint(s_c[tid])) << 32) | (unsigned)tid;
            INSK(key);
        }
        for (int r = 0; r < 8; ++r) {
            ull g = c0;
            #pragma unroll
            for (int off = 1; off < 64; off <<= 1) {
                ull o = __shfl_xor(g, off);
                if (o > g) g = o;
            }
            if (c0 == g && g != 0ULL) {
                c0 = c1; c1 = c2; c2 = c3; c3 = c4; c4 = c5; c5 = c6; c6 = c7; c7 = 0;
            }
            if (tid == 0) s_top8[r] = __uint_as_float((unsigned)(g >> 32));
        }
    }
    __syncthreads();

    // label counts (distinct, reference never counts label 0)
    if (tid < KNN) {
        int fo = (tg != 0) ? 1 : 0;
        if (fo) {
            for (int j = 0; j < tid; ++j)
                if (s_tgt[j] == tg) { fo = 0; break; }
        }
        int c = fo;
        #pragma unroll
        for (int off = 1; off < KNN; off <<= 1) {
            int n2 = __shfl_up(c, off, KNN);
            if (tid >= off) c += n2;
        }
        s_cnt[tid] = (float)c;
    }
    __syncthreads();

    // tiny MLPs, softmaxes, scatter
    if (tid < KNN) {
        // noise_logit: Linear(2,4) -> tanh -> Linear(4,1)
        float noise = b1b[0];
        #pragma unroll
        for (int j = 0; j < 4; ++j) {
            float z = tanhf(W1a[2 * j] * lk + W1a[2 * j + 1] * ls + b1a[j]);
            noise += W1b[j] * z;
        }

        // sim_lambda = W_func . [log(top8) | log_key | log_sel] + b_func
        float sp = W_func[8 + tid] * lk + W_func[40 + tid] * ls;
        if (tid < 8) sp += W_func[tid] * logf(s_top8[tid]);
        #pragma unroll
        for (int off = 16; off; off >>= 1) sp += __shfl_xor(sp, off, KNN);
        float sim = sp + b_func[0];

        // lambda_logit: Linear(64,32) -> tanh -> Linear(32,2); lane = hidden unit
        float h = b2a[tid];
        const float* wr = W2a + tid * 64;
        #pragma unroll 8
        for (int i = 0; i < KNN; ++i) h += wr[i] * s_dist[i];
        #pragma unroll 8
        for (int i = 0; i < KNN; ++i) h += wr[KNN + i] * s_cnt[i];
        h = tanhf(h);
        float p0 = W2b[tid] * h;
        float p1 = W2b[KNN + tid] * h;
        #pragma unroll
        for (int off = 16; off; off >>= 1) {
            p0 += __shfl_xor(p0, off, KNN);
            p1 += __shfl_xor(p1, off, KNN);
        }
        float l0 = p0 + b2b[0];
        float l1 = p1 + b2b[1];

        float tempe = 1.f / (1.f + expf(-l1));          // sigmoid(l1)
        float lam   = 1.f / (1.f + expf(-(l0 - sim)));  // softmax([l0,sim])[0]

        // probs = softmax(-d*tempe + noise) over K
        float logit = -d * tempe + noise;
        float mx = logit;
        #pragma unroll
        for (int off = 16; off; off >>= 1) mx = fmaxf(mx, __shfl_xor(mx, off, KNN));
        float e = expf(logit - mx);
        float se = e;
        #pragma unroll
        for (int off = 16; off; off >>= 1) se += __shfl_xor(se, off, KNN);
        float p = e / se;

        // scatter, last-occurrence-wins on duplicate indices (numpy semantics)
        bool wrte = true;
        for (int j = tid + 1; j < KNN; ++j)
            if (s_tgt[j] == tg) { wrte = false; break; }
        if (wrte) out[(size_t)t * VOCAB + tg] = p;

        if (tid == 0) out[(size_t)TOKENS * VOCAB + t] = lam;
    }
}

extern "C" void kernel_launch(void* const* d_in, const int* in_sizes, int n_in,
                              void* d_out, int out_size, void* d_ws, size_t ws_size,
                              hipStream_t stream) {
    float* ws = (float*)d_ws;   // needs TOKENS*QPT*8*4 = 256 KB

    // big kernel: even blocks scan (read), odd blocks zero (write) -> mixed streams
    k1_big<<<TOKENS * QPT * 2, 256, 0, stream>>>(
        (const float*)d_in[3],   // network_probs
        (float*)d_out,
        ws);

    k2_final<<<TOKENS, 256, 0, stream>>>(
        (const int*)  d_in[0],   // tgt_index
        (const float*)d_in[1],   // knn_dists
        (const float*)d_in[2],   // knn_key_feature
        (const float*)d_in[4],   // network_select_probs
        (const float*)d_in[5],  (const float*)d_in[6],   // W_func, b_func
        (const float*)d_in[7],  (const float*)d_in[8],   // W1a, b1a
        (const float*)d_in[9],  (const float*)d_in[10],  // W1b, b1b
        (const float*)d_in[11], (const float*)d_in[12],  // W2a, b2a
        (const float*)d_in[13], (const float*)d_in[14],  // W2b, b2b
        ws,
        (float*)d_out);
}

// Round 11
// 134.554 us; speedup vs baseline: 1.2660x; 1.1320x over previous
//
#include <hip/hip_runtime.h>

typedef unsigned long long ull;
typedef float f4 __attribute__((ext_vector_type(4)));

#define TOKENS 2048
#define KNN    32
#define VOCAB  32000
#define CAP    2048

// u64 sorted-descending 8-slot insert (c0..c7)
#define INSK(key) do {                                                       \
    ull k_ = (key);                                                          \
    if (k_ > c7) {                                                           \
        ull tmp_;                                                            \
        if (k_ > c0) { tmp_ = c0; c0 = k_; k_ = tmp_; }                      \
        if (k_ > c1) { tmp_ = c1; c1 = k_; k_ = tmp_; }                      \
        if (k_ > c2) { tmp_ = c2; c2 = k_; k_ = tmp_; }                      \
        if (k_ > c3) { tmp_ = c3; c3 = k_; k_ = tmp_; }                      \
        if (k_ > c4) { tmp_ = c4; c4 = k_; k_ = tmp_; }                      \
        if (k_ > c5) { tmp_ = c5; c5 = k_; k_ = tmp_; }                      \
        if (k_ > c6) { tmp_ = c6; c6 = k_; k_ = tmp_; }                      \
        c7 = (k_ > c7) ? k_ : c7;                                            \
    }                                                                        \
} while (0)

// branch-free sorted-descending 8-float insert (fallback path only)
#define INSF(vv) do {                                                        \
    float x_ = (vv);                                                         \
    if (x_ > t7) {                                                           \
        float h_;                                                            \
        h_ = fmaxf(t0, x_); x_ = fminf(t0, x_); t0 = h_;                     \
        h_ = fmaxf(t1, x_); x_ = fminf(t1, x_); t1 = h_;                     \
        h_ = fmaxf(t2, x_); x_ = fminf(t2, x_); t2 = h_;                     \
        h_ = fmaxf(t3, x_); x_ = fminf(t3, x_); t3 = h_;                     \
        h_ = fmaxf(t4, x_); x_ = fminf(t4, x_); t4 = h_;                     \
        h_ = fmaxf(t5, x_); x_ = fminf(t5, x_); t5 = h_;                     \
        h_ = fmaxf(t6, x_); x_ = fminf(t6, x_); t6 = h_;                     \
        t7 = fmaxf(t7, x_);                                                  \
    }                                                                        \
} while (0)

#define MAX4(v_) fmaxf(fmaxf(v_.x, v_.y), fmaxf(v_.z, v_.w))

#define COLLECT(v_) do {                                                     \
    if (v_.x >= T) { int p = atomicAdd(&s_n, 1); if (p < CAP) s_cand[p] = v_.x; } \
    if (v_.y >= T) { int p = atomicAdd(&s_n, 1); if (p < CAP) s_cand[p] = v_.y; } \
    if (v_.z >= T) { int p = atomicAdd(&s_n, 1); if (p < CAP) s_cand[p] = v_.z; } \
    if (v_.w >= T) { int p = atomicAdd(&s_n, 1); if (p < CAP) s_cand[p] = v_.w; } \
} while (0)

// batch of 8: 8 NT loads -> 8 NT zero-stores -> fmax tree
#define BATCH8(kb) do {                                                      \
    f4 v0 = __builtin_nontemporal_load(np4 + tid + (((kb)+0) << 8));         \
    f4 v1 = __builtin_nontemporal_load(np4 + tid + (((kb)+1) << 8));         \
    f4 v2 = __builtin_nontemporal_load(np4 + tid + (((kb)+2) << 8));         \
    f4 v3 = __builtin_nontemporal_load(np4 + tid + (((kb)+3) << 8));         \
    f4 v4 = __builtin_nontemporal_load(np4 + tid + (((kb)+4) << 8));         \
    f4 v5 = __builtin_nontemporal_load(np4 + tid + (((kb)+5) << 8));         \
    f4 v6 = __builtin_nontemporal_load(np4 + tid + (((kb)+6) << 8));         \
    f4 v7 = __builtin_nontemporal_load(np4 + tid + (((kb)+7) << 8));         \
    __builtin_nontemporal_store(z4, o4 + tid + (((kb)+0) << 8));             \
    __builtin_nontemporal_store(z4, o4 + tid + (((kb)+1) << 8));             \
    __builtin_nontemporal_store(z4, o4 + tid + (((kb)+2) << 8));             \
    __builtin_nontemporal_store(z4, o4 + tid + (((kb)+3) << 8));             \
    __builtin_nontemporal_store(z4, o4 + tid + (((kb)+4) << 8));             \
    __builtin_nontemporal_store(z4, o4 + tid + (((kb)+5) << 8));             \
    __builtin_nontemporal_store(z4, o4 + tid + (((kb)+6) << 8));             \
    __builtin_nontemporal_store(z4, o4 + tid + (((kb)+7) << 8));             \
    float m01 = fmaxf(MAX4(v0), MAX4(v1));                                   \
    float m23 = fmaxf(MAX4(v2), MAX4(v3));                                   \
    float m45 = fmaxf(MAX4(v4), MAX4(v5));                                   \
    float m67 = fmaxf(MAX4(v6), MAX4(v7));                                   \
    m = fmaxf(m, fmaxf(fmaxf(m01, m23), fmaxf(m45, m67)));                   \
} while (0)

__global__ __launch_bounds__(256, 6)
void rc_kernel(const int*   __restrict__ tgt_index,
               const float* __restrict__ knn_dists,
               const float* __restrict__ knn_key,
               const float* __restrict__ net_probs,
               const float* __restrict__ net_sel,
               const float* __restrict__ W_func, const float* __restrict__ b_func,
               const float* __restrict__ W1a,    const float* __restrict__ b1a,
               const float* __restrict__ W1b,    const float* __restrict__ b1b,
               const float* __restrict__ W2a,    const float* __restrict__ b2a,
               const float* __restrict__ W2b,    const float* __restrict__ b2b,
               float* __restrict__ out)
{
    const int t   = blockIdx.x;
    const int tid = threadIdx.x;

    __shared__ float s_max[256];
    __shared__ float s_cand[CAP];
    __shared__ int   s_n;
    __shared__ float s_thr;
    __shared__ float s_top8[8];

    if (tid == 0) s_n = 0;

    // ---- per-k loads (lanes 0..31) ----
    int   tg = 0;
    float d = 0.f, lk = 0.f, ls = 0.f;
    if (tid < KNN) {
        tg = tgt_index[t * KNN + tid];
        d  = knn_dists[t * KNN + tid];
        lk = logf(knn_key[t * KNN + tid]);
        ls = logf(net_sel[t * KNN + tid]);
        s_tgt_store: ;
    }
    __shared__ int   s_tgt[KNN];
    __shared__ float s_dist[KNN];
    __shared__ float s_cnt[KNN];
    if (tid < KNN) { s_tgt[tid] = tg; s_dist[tid] = d; }

    // ---- Phase 1: batched NT scan + NT zero-fill (8000 f4: k=0..30 all, k=31 tid<64) ----
    const f4* np4 = (const f4*)(net_probs + (size_t)t * VOCAB);
    f4*       o4  = (f4*)(out + (size_t)t * VOCAB);
    const f4  z4  = (f4){0.f, 0.f, 0.f, 0.f};
    float m = 0.f;

    BATCH8(0);
    BATCH8(8);
    BATCH8(16);
    // k = 24..30 (7)
    {
        f4 v0 = __builtin_nontemporal_load(np4 + tid + (24 << 8));
        f4 v1 = __builtin_nontemporal_load(np4 + tid + (25 << 8));
        f4 v2 = __builtin_nontemporal_load(np4 + tid + (26 << 8));
        f4 v3 = __builtin_nontemporal_load(np4 + tid + (27 << 8));
        f4 v4 = __builtin_nontemporal_load(np4 + tid + (28 << 8));
        f4 v5 = __builtin_nontemporal_load(np4 + tid + (29 << 8));
        f4 v6 = __builtin_nontemporal_load(np4 + tid + (30 << 8));
        __builtin_nontemporal_store(z4, o4 + tid + (24 << 8));
        __builtin_nontemporal_store(z4, o4 + tid + (25 << 8));
        __builtin_nontemporal_store(z4, o4 + tid + (26 << 8));
        __builtin_nontemporal_store(z4, o4 + tid + (27 << 8));
        __builtin_nontemporal_store(z4, o4 + tid + (28 << 8));
        __builtin_nontemporal_store(z4, o4 + tid + (29 << 8));
        __builtin_nontemporal_store(z4, o4 + tid + (30 << 8));
        float m01 = fmaxf(MAX4(v0), MAX4(v1));
        float m23 = fmaxf(MAX4(v2), MAX4(v3));
        float m45 = fmaxf(MAX4(v4), MAX4(v5));
        m = fmaxf(m, fmaxf(fmaxf(m01, m23), fmaxf(m45, MAX4(v6))));
    }
    if (tid < 64) {   // tail k = 31
        f4 v = __builtin_nontemporal_load(np4 + tid + (31 << 8));
        __builtin_nontemporal_store(z4, o4 + tid + (31 << 8));
        m = fmaxf(m, MAX4(v));
    }
    s_max[tid] = m;
    __syncthreads();

    // ---- Phase 2: T = 8th largest of 256 stripe maxes (one wave) ----
    if (tid < 64) {
        ull c0 = 0, c1 = 0, c2 = 0, c3 = 0, c4 = 0, c5 = 0, c6 = 0, c7 = 0;
        #pragma unroll
        for (int k = 0; k < 4; ++k) {
            int idx = tid + (k << 6);
            ull key = (((ull)__float_as_uint(s_max[idx])) << 32) | (unsigned)idx;
            INSK(key);
        }
        ull g = 0;
        for (int r = 0; r < 8; ++r) {
            g = c0;
            #pragma unroll
            for (int off = 1; off < 64; off <<= 1) {
                ull o = __shfl_xor(g, off);
                if (o > g) g = o;
            }
            if (c0 == g) {
                c0 = c1; c1 = c2; c2 = c3; c3 = c4; c4 = c5; c5 = c6; c6 = c7; c7 = 0;
            }
        }
        if (tid == 0) s_thr = __uint_as_float((unsigned)(g >> 32));
    }
    __syncthreads();
    const float T = s_thr;

    // ---- Phase 3: selective re-scan (only ~8/256 qualifying stripes, ~4 KB) ----
    if (m >= T) {
        for (int k = 0; k < 31; ++k) {
            f4 v = np4[tid + (k << 8)];
            COLLECT(v);
        }
        if (tid < 64) {
            f4 v = np4[tid + (31 << 8)];
            COLLECT(v);
        }
    }
    __syncthreads();
    const int n = s_n;

    if (n <= CAP) {
        if (tid < 64) {
            ull c0 = 0, c1 = 0, c2 = 0, c3 = 0, c4 = 0, c5 = 0, c6 = 0, c7 = 0;
            for (int i = tid; i < n; i += 64) {
                ull key = (((ull)__float_as_uint(s_cand[i])) << 32) | (unsigned)i;
                INSK(key);
            }
            for (int r = 0; r < 8; ++r) {
                ull g = c0;
                #pragma unroll
                for (int off = 1; off < 64; off <<= 1) {
                    ull o = __shfl_xor(g, off);
                    if (o > g) g = o;
                }
                if (c0 == g && g != 0ULL) {
                    c0 = c1; c1 = c2; c2 = c3; c3 = c4; c4 = c5; c5 = c6; c6 = c7; c7 = 0;
                }
                if (tid == 0) s_top8[r] = __uint_as_float((unsigned)(g >> 32));
            }
        }
    } else {
        // fallback (adversarial ties): per-thread exact top-8 + full merge
        float t0 = 0.f, t1 = 0.f, t2 = 0.f, t3 = 0.f,
              t4 = 0.f, t5 = 0.f, t6 = 0.f, t7 = 0.f;
        for (int k = 0; k < 31; ++k) {
            f4 v = np4[tid + (k << 8)];
            if (MAX4(v) > t7) { INSF(v.x); INSF(v.y); INSF(v.z); INSF(v.w); }
        }
        if (tid < 64) {
            f4 v = np4[tid + (31 << 8)];
            if (MAX4(v) > t7) { INSF(v.x); INSF(v.y); INSF(v.z); INSF(v.w); }
        }
        __syncthreads();
        s_cand[tid * 8 + 0] = t0;  s_cand[tid * 8 + 1] = t1;
        s_cand[tid * 8 + 2] = t2;  s_cand[tid * 8 + 3] = t3;
        s_cand[tid * 8 + 4] = t4;  s_cand[tid * 8 + 5] = t5;
        s_cand[tid * 8 + 6] = t6;  s_cand[tid * 8 + 7] = t7;
        __syncthreads();
        if (tid < 64) {
            ull c0 = 0, c1 = 0, c2 = 0, c3 = 0, c4 = 0, c5 = 0, c6 = 0, c7 = 0;
            for (int k = 0; k < 32; ++k) {
                int idx = tid + (k << 6);
                ull key = (((ull)__float_as_uint(s_cand[idx])) << 32) | (unsigned)idx;
                INSK(key);
            }
            for (int r = 0; r < 8; ++r) {
                ull g = c0;
                #pragma unroll
                for (int off = 1; off < 64; off <<= 1) {
                    ull o = __shfl_xor(g, off);
                    if (o > g) g = o;
                }
                if (c0 == g) {
                    c0 = c1; c1 = c2; c2 = c3; c3 = c4; c4 = c5; c5 = c6; c6 = c7; c7 = 0;
                }
                if (tid == 0) s_top8[r] = __uint_as_float((unsigned)(g >> 32));
            }
        }
    }
    __syncthreads();

    // ---- Phase 4a: label counts (distinct, reference never counts label 0) ----
    if (tid < KNN) {
        int fo = (tg != 0) ? 1 : 0;
        if (fo) {
            for (int j = 0; j < tid; ++j)
                if (s_tgt[j] == tg) { fo = 0; break; }
        }
        int c = fo;
        #pragma unroll
        for (int off = 1; off < KNN; off <<= 1) {
            int n2 = __shfl_up(c, off, KNN);
            if (tid >= off) c += n2;
        }
        s_cnt[tid] = (float)c;
    }
    __syncthreads();

    // ---- Phase 4b: tiny MLPs, softmaxes, scatter ----
    if (tid < KNN) {
        // noise_logit: Linear(2,4) -> tanh -> Linear(4,1)
        float noise = b1b[0];
        #pragma unroll
        for (int j = 0; j < 4; ++j) {
            float z = tanhf(W1a[2 * j] * lk + W1a[2 * j + 1] * ls + b1a[j]);
            noise += W1b[j] * z;
        }

        // sim_lambda = W_func . [log(top8) | log_key | log_sel] + b_func
        float sp = W_func[8 + tid] * lk + W_func[40 + tid] * ls;
        if (tid < 8) sp += W_func[tid] * logf(s_top8[tid]);
        #pragma unroll
        for (int off = 16; off; off >>= 1) sp += __shfl_xor(sp, off, KNN);
        float sim = sp + b_func[0];

        // lambda_logit: Linear(64,32) -> tanh -> Linear(32,2); lane = hidden unit
        float h = b2a[tid];
        const float* wr = W2a + tid * 64;
        #pragma unroll 8
        for (int i = 0; i < KNN; ++i) h += wr[i] * s_dist[i];
        #pragma unroll 8
        for (int i = 0; i < KNN; ++i) h += wr[KNN + i] * s_cnt[i];
        h = tanhf(h);
        float p0 = W2b[tid] * h;
        float p1 = W2b[KNN + tid] * h;
        #pragma unroll
        for (int off = 16; off; off >>= 1) {
            p0 += __shfl_xor(p0, off, KNN);
            p1 += __shfl_xor(p1, off, KNN);
        }
        float l0 = p0 + b2b[0];
        float l1 = p1 + b2b[1];

        float tempe = 1.f / (1.f + expf(-l1));          // sigmoid(l1)
        float lam   = 1.f / (1.f + expf(-(l0 - sim)));  // softmax([l0,sim])[0]

        // probs = softmax(-d*tempe + noise) over K
        float logit = -d * tempe + noise;
        float mx = logit;
        #pragma unroll
        for (int off = 16; off; off >>= 1) mx = fmaxf(mx, __shfl_xor(mx, off, KNN));
        float e = expf(logit - mx);
        float se = e;
        #pragma unroll
        for (int off = 16; off; off >>= 1) se += __shfl_xor(se, off, KNN);
        float p = e / se;

        // scatter, last-occurrence-wins on duplicate indices (numpy semantics)
        bool wrte = true;
        for (int j = tid + 1; j < KNN; ++j)
            if (s_tgt[j] == tg) { wrte = false; break; }
        if (wrte) out[(size_t)t * VOCAB + tg] = p;

        if (tid == 0) out[(size_t)TOKENS * VOCAB + t] = lam;
    }
}

extern "C" void kernel_launch(void* const* d_in, const int* in_sizes, int n_in,
                              void* d_out, int out_size, void* d_ws, size_t ws_size,
                              hipStream_t stream) {
    rc_kernel<<<TOKENS, 256, 0, stream>>>(
        (const int*)  d_in[0],   // tgt_index
        (const float*)d_in[1],   // knn_dists
        (const float*)d_in[2],   // knn_key_feature
        (const float*)d_in[3],   // network_probs
        (const float*)d_in[4],   // network_select_probs
        (const float*)d_in[5],  (const float*)d_in[6],   // W_func, b_func
        (const float*)d_in[7],  (const float*)d_in[8],   // W1a, b1a
        (const float*)d_in[9],  (const float*)d_in[10],  // W1b, b1b
        (const float*)d_in[11], (const float*)d_in[12],  // W2a, b2a
        (const float*)d_in[13], (const float*)d_in[14],  // W2b, b2b
        (float*)d_out);
}